// Round 14
// baseline (14.478 us; speedup 1.0000x reference)
//
#include <hip/hip_runtime.h>
#include <cmath>

// Problem constants (match the reference)
#define HH 256
#define WW 256
#define NG 1024
#define NB 2
#define NTILE 256            // tiles per batch (32x8 px)
static constexpr float FXc = 300.0f;
static constexpr float FYc = 300.0f;
static constexpr float CXc = 128.0f;
static constexpr float CYc = 128.0f;
static constexpr float EPSc = 1e-8f;
static constexpr float LOG2E = 1.4426950408889634f;

#if defined(__has_builtin)
#if __has_builtin(__builtin_amdgcn_exp2f)
#define FAST_EXP2(x) __builtin_amdgcn_exp2f(x)
#else
#define FAST_EXP2(x) exp2f(x)
#endif
#else
#define FAST_EXP2(x) exp2f(x)
#endif

typedef __attribute__((ext_vector_type(2))) float f32x2;
static __device__ __forceinline__ f32x2 splat2(float s) {
    f32x2 v; v.x = s; v.y = s; return v;
}
static __device__ __forceinline__ f32x2 pkshfl_xor(f32x2 v, int m) {
    f32x2 r; r.x = __shfl_xor(v.x, m); r.y = __shfl_xor(v.y, m); return r;
}

// SINGLE fused kernel (R13 + 4x2-oct per thread, 2 LDS reads / 8 px):
//   grid = 512 blocks (NB*NTILE), 512 threads (8 waves), 32x8-px tile.
//   Phase 1 (cull+stage): UNCHANGED proven cull (wave w projects
//     [w*128,(w+1)*128) in 2 rounds; exact circle-rect test, rcut=7.8987*s
//     i.e. k*rcut^2=-45; ballot+prefix deterministic g-ascending
//     compaction). Color word now carries G4 = 2^(4k) in .w.
//     Pad np to x16 with sentinel (k=0,A=-500 -> w=0; G4=1).
//     NOTE: cull rejects inf/NaN projections (comparison false), so every
//     staged gaussian has |u - tile| <= ~200 px -> d10u <= ~12, all
//     exponent paths finite; clamps below are belt-and-suspenders.
//   Phase 2 (render): thread = (oct t [0,32), h [0,16)): 4x2 pixel oct =
//     two 2x2 quads at x and x+2. Quad B derived, not recomputed:
//       e02 = e00 + 2*(d10u + k)      (exact: 2nd difference of e is 2k)
//       ExB = Ex * G4                 (d10(x+2) = d10 + 4k)
//     -> 4 exp + 2 b128 reads per 8 px (was 3 exp + 3 reads per 4 px).
//     16-way gaussian split (g = i*16+h), 16 named f32x2 accumulators,
//     pk accumulation; 4-stage butterfly; lanes h<8 write the oct's 8 px.
//   Culled-total error bound <= 1024*2^-45 -> ~0.003 even where den~EPS.
__global__ __launch_bounds__(512) void render_kernel(
    const float* __restrict__ positions,   // [N,3]
    const float* __restrict__ colors,      // [N,3]
    const float* __restrict__ opacities,   // [N,1]
    const float* __restrict__ scales,      // [N,1]
    const float* __restrict__ qvec,        // [B,4]
    const float* __restrict__ tvec,        // [B,3]
    float* __restrict__ out)               // [B,3,H,W]
{
    __shared__ float4 gs0[NG];   // (k, kx, ky, A)
    __shared__ float4 gsC[NG];   // (r, g, b, G4)
    __shared__ int wcnt[8];

    const int b = blockIdx.x >> 8;        // 256 blocks per batch
    int tile = blockIdx.x & 255;
    if (b) tile ^= 128;                   // decorrelate per-CU load across batches
    const int x0 = (tile & 7) << 5;       // 8 tiles of 32 px in x
    const int y0 = (tile >> 3) << 3;      // 32 tiles of 8 px in y
    const float cx = (float)x0 + 15.5f;
    const float cy = (float)y0 + 3.5f;

    // --- wave-uniform rotation setup ---
    float qw = qvec[b * 4 + 0], qx = qvec[b * 4 + 1];
    float qy = qvec[b * 4 + 2], qz = qvec[b * 4 + 3];
    float rin = rsqrtf(qw * qw + qx * qx + qy * qy + qz * qz);
    qw *= rin; qx *= rin; qy *= rin; qz *= rin;
    const float r00 = 1.0f - 2.0f * (qy * qy + qz * qz);
    const float r01 = 2.0f * (qx * qy - qz * qw);
    const float r02 = 2.0f * (qx * qz + qy * qw);
    const float r10 = 2.0f * (qx * qy + qz * qw);
    const float r11 = 1.0f - 2.0f * (qx * qx + qz * qz);
    const float r12 = 2.0f * (qy * qz - qx * qw);
    const float r20 = 2.0f * (qx * qz - qy * qw);
    const float r21 = 2.0f * (qy * qz + qx * qw);
    const float r22 = 1.0f - 2.0f * (qx * qx + qy * qy);
    const float t0 = tvec[b * 3 + 0], t1 = tvec[b * 3 + 1], t2 = tvec[b * 3 + 2];

    // --- phase 1: project + cull + deterministic compaction ---
    const int wv = threadIdx.x >> 6;      // wave id [0,8)
    const int lane = threadIdx.x & 63;

    float4 pa0, pa1, pc0, pc1;            // buffered kept params (named: rule #20)
    int pos0 = -1, pos1 = -1;
    int cnt = 0;                          // wave-local running count

    #pragma unroll
    for (int r = 0; r < 2; ++r) {
        const int g = wv * 128 + r * 64 + lane;
        const float X = positions[g * 3 + 0];
        const float Y = positions[g * 3 + 1];
        const float Z = positions[g * 3 + 2];
        const float cxp = r00 * X + r01 * Y + r02 * Z + t0;
        const float cyp = r10 * X + r11 * Y + r12 * Z + t1;
        const float czp = r20 * X + r21 * Y + r22 * Z + t2;
        const float iz = 1.0f / czp;
        const float ux = cxp * iz * FXc + CXc;
        const float uy = cyp * iz * FYc + CYc;
        const float s = scales[g];
        const float rcut = 7.8987f * s;
        const float ddx = fmaxf(fabsf(ux - cx) - 15.5f, 0.0f);
        const float ddy = fmaxf(fabsf(uy - cy) - 3.5f, 0.0f);
        const bool in = fmaf(ddx, ddx, ddy * ddy) <= rcut * rcut;
        const unsigned long long m = __ballot(in);
        if (in) {
            const float k = -0.5f * LOG2E / (s * s);
            const float lop = __log2f(opacities[g]);
            const float kx = -2.0f * k * ux;
            const float ky = -2.0f * k * uy;
            const float A = fmaf(k, fmaf(ux, ux, uy * uy), lop);
            const float G4 = exp2f(4.0f * k);
            const int pre = cnt + __popcll(m & ((1ull << lane) - 1ull));
            if (r == 0) {
                pa0 = make_float4(k, kx, ky, A);
                pc0 = make_float4(colors[g * 3 + 0], colors[g * 3 + 1],
                                  colors[g * 3 + 2], G4);
                pos0 = pre;
            } else {
                pa1 = make_float4(k, kx, ky, A);
                pc1 = make_float4(colors[g * 3 + 0], colors[g * 3 + 1],
                                  colors[g * 3 + 2], G4);
                pos1 = pre;
            }
        }
        cnt += __popcll(m);
    }
    if (lane == 0) wcnt[wv] = cnt;
    __syncthreads();

    int base = 0, npTot = 0;
    #pragma unroll
    for (int j = 0; j < 8; ++j) {
        const int c = wcnt[j];
        if (j < wv) base += c;
        npTot += c;
    }
    if (pos0 >= 0) { gs0[base + pos0] = pa0; gsC[base + pos0] = pc0; }
    if (pos1 >= 0) { gs0[base + pos1] = pa1; gsC[base + pos1] = pc1; }
    const int np = (npTot + 15) & ~15;    // pad to multiple of 16
    if ((int)threadIdx.x < np - npTot) {  // sentinel: w=0, Ex=Ey=1, G4=1
        gs0[npTot + threadIdx.x] = make_float4(0.0f, 0.0f, 0.0f, -500.0f);
        gsC[npTot + threadIdx.x] = make_float4(0.0f, 0.0f, 0.0f, 1.0f);
    }
    __syncthreads();

    // --- phase 2: render (4x2 oct per thread, 16-way split) ---
    const int h = threadIdx.x & 15;       // gaussian split lane [0,16)
    const int t = threadIdx.x >> 4;       // oct id [0,32)
    const int octx = x0 + ((t & 7) << 2); // 8 octs of 4 px in x
    const int octy = y0 + ((t >> 3) << 1);// 4 octs of 2 px in y
    const float px = (float)octx;
    const float py = (float)octy;
    const float c2 = fmaf(px, px, py * py);
    const float u = fmaf(2.0f, px, 1.0f);
    const float v = fmaf(2.0f, py, 1.0f);

    // 16 named packed accumulators: quad0 @ x, quad1 @ x+2;
    // A-half = row y (px pair), B-half = row y+1
    f32x2 zz = {0.f, 0.f};
    f32x2 d0A = zz, d0B = zz, r0A = zz, r0B = zz;
    f32x2 g0A = zz, g0B = zz, b0A = zz, b0B = zz;
    f32x2 d1A = zz, d1B = zz, r1A = zz, r1B = zz;
    f32x2 g1A = zz, g1B = zz, b1A = zz, b1B = zz;

    const int iters = np >> 4;
    #pragma unroll 2
    for (int i = 0; i < iters; ++i) {
        const int g = (i << 4) + h;
        const float4 q0 = gs0[g];
        const float4 qc = gsC[g];
        const float k = q0.x;
        float e00 = fmaf(k, c2, q0.w);
        e00 = fmaf(q0.y, px, e00);
        e00 = fmaf(q0.z, py, e00);
        const float d10u = fmaf(k, u, q0.y);      // e(x+1)-e(x)
        const float d01u = fmaf(k, v, q0.z);      // e(y+1)-e(y)
        const float e02 = fmaf(2.0f, d10u + k, e00);  // e(x+2), exact, <=0
        const float d10 = fminf(d10u, 126.0f);
        const float d01 = fminf(d01u, 126.0f);
        const float w00 = FAST_EXP2(e00);
        const float Ex  = FAST_EXP2(d10);
        const float Ey  = FAST_EXP2(d01);
        const float w02 = FAST_EXP2(e02);
        const float ExB = Ex * qc.w;              // exp2(d10+4k)
        const float w10 = w00 * Ex;
        const float w12 = w02 * ExB;
        f32x2 WA0; WA0.x = w00; WA0.y = w10;      // quad0 row y
        f32x2 WA1; WA1.x = w02; WA1.y = w12;      // quad1 row y
        const f32x2 ey2 = splat2(Ey);
        const f32x2 WB0 = WA0 * ey2;              // quad0 row y+1
        const f32x2 WB1 = WA1 * ey2;              // quad1 row y+1
        const f32x2 rr = splat2(qc.x);
        const f32x2 gg = splat2(qc.y);
        const f32x2 bb = splat2(qc.z);
        d0A += WA0; d0B += WB0; d1A += WA1; d1B += WB1;
        r0A = __builtin_elementwise_fma(WA0, rr, r0A);
        r0B = __builtin_elementwise_fma(WB0, rr, r0B);
        r1A = __builtin_elementwise_fma(WA1, rr, r1A);
        r1B = __builtin_elementwise_fma(WB1, rr, r1B);
        g0A = __builtin_elementwise_fma(WA0, gg, g0A);
        g0B = __builtin_elementwise_fma(WB0, gg, g0B);
        g1A = __builtin_elementwise_fma(WA1, gg, g1A);
        g1B = __builtin_elementwise_fma(WB1, gg, g1B);
        b0A = __builtin_elementwise_fma(WA0, bb, b0A);
        b0B = __builtin_elementwise_fma(WB0, bb, b0B);
        b1A = __builtin_elementwise_fma(WA1, bb, b1A);
        b1B = __builtin_elementwise_fma(WB1, bb, b1B);
    }

    // --- butterfly combine across the 16-lane split group ---
    #pragma unroll
    for (int m = 1; m <= 8; m <<= 1) {
        d0A += pkshfl_xor(d0A, m); d0B += pkshfl_xor(d0B, m);
        d1A += pkshfl_xor(d1A, m); d1B += pkshfl_xor(d1B, m);
        r0A += pkshfl_xor(r0A, m); r0B += pkshfl_xor(r0B, m);
        r1A += pkshfl_xor(r1A, m); r1B += pkshfl_xor(r1B, m);
        g0A += pkshfl_xor(g0A, m); g0B += pkshfl_xor(g0B, m);
        g1A += pkshfl_xor(g1A, m); g1B += pkshfl_xor(g1B, m);
        b0A += pkshfl_xor(b0A, m); b0B += pkshfl_xor(b0B, m);
        b1A += pkshfl_xor(b1A, m); b1B += pkshfl_xor(b1B, m);
    }

    // --- epilogue: lanes h<8 write the oct's 8 pixels ---
    if (h < 8) {
        const int xo = h & 3;             // 0..3 within oct
        const int yo = h >> 2;            // row 0/1
        const bool q1 = xo >= 2;          // quad at x+2?
        const bool rowB = yo != 0;
        const f32x2 dsel = q1 ? (rowB ? d1B : d1A) : (rowB ? d0B : d0A);
        const f32x2 rsel = q1 ? (rowB ? r1B : r1A) : (rowB ? r0B : r0A);
        const f32x2 gsel = q1 ? (rowB ? g1B : g1A) : (rowB ? g0B : g0A);
        const f32x2 bsel = q1 ? (rowB ? b1B : b1A) : (rowB ? b0B : b0A);
        const bool odd = (xo & 1) != 0;
        const float den = odd ? dsel.y : dsel.x;
        const float cr  = odd ? rsel.y : rsel.x;
        const float cg  = odd ? gsel.y : gsel.x;
        const float cb  = odd ? bsel.y : bsel.x;
        const float inv = 1.0f / (den + EPSc);
        const int pxx = octx + xo;
        const int pyy = octy + yo;
        const size_t o = (size_t)b * 3 * 65536 + (size_t)pyy * WW + pxx;
        out[o]           = cr * inv;
        out[o + 65536]   = cg * inv;
        out[o + 131072]  = cb * inv;
    }
}

extern "C" void kernel_launch(void* const* d_in, const int* in_sizes, int n_in,
                              void* d_out, int out_size, void* d_ws, size_t ws_size,
                              hipStream_t stream) {
    const float* positions = (const float*)d_in[0];
    const float* colors    = (const float*)d_in[1];
    const float* opacities = (const float*)d_in[2];
    const float* scales    = (const float*)d_in[3];
    const float* qvec      = (const float*)d_in[4];
    const float* tvec      = (const float*)d_in[5];
    float* out = (float*)d_out;

    render_kernel<<<dim3(NB * NTILE), dim3(512), 0, stream>>>(
        positions, colors, opacities, scales, qvec, tvec, out);
}